// Round 5
// baseline (113.824 us; speedup 1.0000x reference)
//
#include <hip/hip_runtime.h>

// Chamfer distance, B=8, N=M=8192, D=3, fp32 — R16: TRANSPOSE-FUSED.
// Compute each 8192x8192 distance tile ONCE; extract row-mins (x-side) AND
// col-mins (y-side) from the same 32x32 MFMA accumulator. Halves MFMA work,
// halves B-tile loads/steps vs R12-R15 (which were stall-bound with an
// invariant ~44us regardless of schedule).
//
// dist[i][j] = nx_i + ny_j - 2 x_i.y_j; out = mean(min_j) + mean(min_i).
// K=16 bf16-split packing (validated R8-R15, absmax 0.0):
//   A row = [ah0 ah1 ah2 ah0 ah1 ah2 al0 al1 | al2 nxh nxl 1 1 0 0 0]
//   B col = [yh0 yh1 yh2 yl0 yl1 yl2 yh0 yh1 | yh2 1 1 nyh nyl 0 0 0]
//
// C/D layout (validated): col = lane&31, row = (reg&3)+8*(reg>>2)+4*(lane>>5).
// Row-min: elementwise fold into rm[16] (as before).
// Col-min: per-lane fold of the two A-tile accs (32 regs = 32 of the 64 wave
// rows for column lane&31) + __shfl_xor(32) -> col-min over 64 rows; store
// once per tile into a wave-private LDS slab (no init, no atomics), block
// combine after the loop, 32 row-block partials folded in final kernel.

#define B_ 8
#define N_ 8192
#define PTS (B_ * N_)            // 65536 points per cloud = total rows
#define NTILES 2048              // 32-point tiles per cloud (65536/32)
#define TPB 256

typedef short bf16x8 __attribute__((ext_vector_type(8)));
typedef float f32x16 __attribute__((ext_vector_type(16)));

__device__ __forceinline__ unsigned b16(float f) {   // fp32 -> bf16 bits (RNE)
  unsigned u = __float_as_uint(f);
  return (u + 0x7FFFu + ((u >> 16) & 1u)) >> 16;
}
__device__ __forceinline__ float bf(unsigned h) { return __uint_as_float(h << 16); }

// ---- one-shot fragment packing: 131072 tasks (A from x, B from y) ----
__global__ __launch_bounds__(256) void pack_frags_k(
    const float* __restrict__ x, const float* __restrict__ y,
    uint4* __restrict__ afrag, uint4* __restrict__ bfrag) {
  const unsigned one = 0x3F80u;
  int t = blockIdx.x * 256 + threadIdx.x;   // 0 .. 131071
  int kind = t >> 16;                        // 0 = A-frag (x), 1 = B-frag (y)
  int p = t & 65535;
  int tile = p >> 5, m = p & 31;
  if (kind == 0) {
    const float* po = x + 3 * p;             // row cloud = x
    float v0 = po[0], v1 = po[1], v2 = po[2];
    float nv = fmaf(v0, v0, fmaf(v1, v1, v2 * v2));
    float a0 = -2.0f * v0, a1 = -2.0f * v1, a2 = -2.0f * v2;
    unsigned ah0 = b16(a0), ah1 = b16(a1), ah2 = b16(a2);
    unsigned al0 = b16(a0 - bf(ah0)), al1 = b16(a1 - bf(ah1)), al2 = b16(a2 - bf(ah2));
    unsigned nh = b16(nv), nl = b16(nv - bf(nh));
    afrag[tile * 64 + m]      = make_uint4(ah0 | (ah1 << 16), ah2 | (ah0 << 16),
                                           ah1 | (ah2 << 16), al0 | (al1 << 16));
    afrag[tile * 64 + 32 + m] = make_uint4(al2 | (nh << 16), nl | (one << 16), one, 0u);
  } else {
    const float* pc = y + 3 * p;             // candidate cloud = y
    float c0 = pc[0], c1 = pc[1], c2 = pc[2];
    float nc = fmaf(c0, c0, fmaf(c1, c1, c2 * c2));
    unsigned yh0 = b16(c0), yh1 = b16(c1), yh2 = b16(c2);
    unsigned yl0 = b16(c0 - bf(yh0)), yl1 = b16(c1 - bf(yh1)), yl2 = b16(c2 - bf(yh2));
    unsigned nh = b16(nc), nl = b16(nc - bf(nh));
    bfrag[tile * 64 + m]      = make_uint4(yh0 | (yh1 << 16), yh2 | (yl0 << 16),
                                           yl1 | (yl2 << 16), yh0 | (yh1 << 16));
    bfrag[tile * 64 + 32 + m] = make_uint4(yh2 | (one << 16), one | (nh << 16), nl, 0u);
  }
}

// ---- main: 1024 blocks x 256 thr; block = 4 waves x 64 rows = 256 rows of x,
// scans one candidate quarter (2048 y-points = 64 prepacked tiles). ----
__global__ __launch_bounds__(TPB, 3) void chamfer_main_k(
    const uint4* __restrict__ afrag, const uint4* __restrict__ bfrag,
    float* __restrict__ grow, float* __restrict__ gcol) {
  __shared__ float cmw[4][2048];             // wave-private col-min slabs, 32KB

  int t = threadIdx.x, lane = t & 63, w = t >> 6;    // 4 waves
  int b0 = blockIdx.x;
  // XCD-bijective swizzle (1024 blocks % 8 == 0): consecutive effective ids
  // on one XCD share (batch, quarter) families -> hot B set L2-resident.
  int eff = ((b0 & 7) << 7) | (b0 >> 3);
  int q = eff & 3;                 // candidate quarter (64 B-tiles)
  int rg = eff >> 2;               // 0..255 : 256-row groups
  int batch = rg >> 5;             // 0..7
  int rb = rg & 31;                // 256-row block within batch

  // A-frags: 2 row-tiles (64 rows) per wave, straight from prepacked global.
  int tileA0 = batch * 256 + rb * 8 + w * 2;
  bf16x8 A0 = __builtin_bit_cast(bf16x8, afrag[tileA0 * 64 + lane]);
  bf16x8 A1 = __builtin_bit_cast(bf16x8, afrag[(tileA0 + 1) * 64 + lane]);

  const uint4* bt = bfrag + (size_t)(batch * 256 + q * 64) * 64 + lane;

  f32x16 z, rm0, rm1;
#pragma unroll
  for (int r = 0; r < 16; ++r) { z[r] = 0.0f; rm0[r] = 1e30f; rm1[r] = 1e30f; }

#define LD(ti) __builtin_bit_cast(bf16x8, bt[(ti) * 64])
#define MF(Aa, Bb) __builtin_amdgcn_mfma_f32_32x32x16_bf16(Aa, Bb, z, 0, 0, 0)

#pragma unroll 2
  for (int j = 0; j < 64; j += 2) {          // 64 tiles, 2 per iter
    bf16x8 B0 = LD(j), B1 = LD(j + 1);
    f32x16 a00 = MF(A0, B0), a10 = MF(A1, B0);
    f32x16 a01 = MF(A0, B1), a11 = MF(A1, B1);
    // row-min fold (x-side): rows of A0 -> rm0, rows of A1 -> rm1.
#pragma unroll
    for (int r = 0; r < 16; ++r) {
      rm0[r] = fminf(fminf(rm0[r], a00[r]), a01[r]);   // v_min3_f32
      rm1[r] = fminf(fminf(rm1[r], a10[r]), a11[r]);   // v_min3_f32
    }
    // col-min fold (y-side): per-lane over both A-tiles' accs = 32 of the
    // 64 wave rows for column lane&31; xor32 merges the other half.
    float c0 = 1e30f, c1 = 1e30f;
#pragma unroll
    for (int r = 0; r < 16; ++r) {
      c0 = fminf(fminf(c0, a00[r]), a10[r]);           // v_min3_f32
      c1 = fminf(fminf(c1, a01[r]), a11[r]);           // v_min3_f32
    }
    c0 = fminf(c0, __shfl_xor(c0, 32, 64));
    c1 = fminf(c1, __shfl_xor(c1, 32, 64));
    if (lane < 32) {                          // each slot written exactly once
      cmw[w][j * 32 + lane] = c0;
      cmw[w][(j + 1) * 32 + lane] = c1;
    }
  }
#undef LD
#undef MF

  // ---- row epilogue: fold 32 cols per half (butterfly), store row-mins ----
#pragma unroll
  for (int msk = 1; msk <= 16; msk <<= 1)
#pragma unroll
    for (int r = 0; r < 16; ++r) {
      rm0[r] = fminf(rm0[r], __shfl_xor(rm0[r], msk, 64));
      rm1[r] = fminf(rm1[r], __shfl_xor(rm1[r], msk, 64));
    }

  int rowbase = batch * N_ + rb * 256 + w * 64;
  float* gp = grow + (size_t)q * PTS + rowbase;
  if ((lane & 31) == 0) {                      // lanes 0 and 32 (h = lane>>5)
    int h = lane >> 5;
#pragma unroll
    for (int r = 0; r < 16; ++r) {
      int rr = (r & 3) + 8 * (r >> 2) + 4 * h;
      gp[rr] = rm0[r];
      gp[32 + rr] = rm1[r];
    }
  }

  // ---- col epilogue: combine 4 wave slabs, store block's col partials ----
  __syncthreads();
  float* gc = gcol + (size_t)(batch * 32 + rb) * N_ + q * 2048;
#pragma unroll
  for (int k = 0; k < 8; ++k) {
    int c = k * 256 + t;
    gc[c] = fminf(fminf(cmw[0][c], cmw[1][c]), fminf(cmw[2][c], cmw[3][c]));
  }
}

// ---- final: rows = min over 4 quarters; cols = min over 32 row-blocks ----
__global__ __launch_bounds__(256) void chamfer_final_k(
    const float* __restrict__ grow, const float* __restrict__ gcol,
    float* __restrict__ out) {
  int t = blockIdx.x * 256 + threadIdx.x;    // 0 .. 65535 (one per y-point)
  // col part: y-point t -> batch = t>>13, col within batch = t&8191.
  int batch = t >> 13, c = t & 8191;
  const float* gcb = gcol + (size_t)batch * 32 * N_ + c;
  float cv = 1e30f;
#pragma unroll
  for (int s = 0; s < 32; ++s) cv = fminf(cv, gcb[(size_t)s * N_]);
  float acc = cv;
  // row part: first 16384 threads each fold one float4 across 4 quarters.
  if (t < (PTS / 4)) {
    const float4* g4 = reinterpret_cast<const float4*>(grow);
    float4 a = g4[t];
    float4 b = g4[t + (PTS / 4)];
    float4 c4 = g4[t + 2 * (PTS / 4)];
    float4 d = g4[t + 3 * (PTS / 4)];
    acc += fminf(fminf(a.x, b.x), fminf(c4.x, d.x))
         + fminf(fminf(a.y, b.y), fminf(c4.y, d.y))
         + fminf(fminf(a.z, b.z), fminf(c4.z, d.z))
         + fminf(fminf(a.w, b.w), fminf(c4.w, d.w));
  }
  for (int off = 32; off > 0; off >>= 1) acc += __shfl_down(acc, off, 64);
  __shared__ float red[4];
  int lane = threadIdx.x & 63, wv = threadIdx.x >> 6;
  if (lane == 0) red[wv] = acc;
  __syncthreads();
  if (threadIdx.x == 0) {
    float tt = (red[0] + red[1]) + (red[2] + red[3]);
    atomicAdd(out, tt * (1.0f / (float)PTS));
  }
}

extern "C" void kernel_launch(void* const* d_in, const int* in_sizes, int n_in,
                              void* d_out, int out_size, void* d_ws, size_t ws_size,
                              hipStream_t stream) {
  const float* x = (const float*)d_in[0];
  const float* y = (const float*)d_in[1];
  float* out = (float*)d_out;
  // ws layout: grow 1MB | gcol 8MB | afrag 2MB | bfrag 2MB  (13MB total)
  float* grow = (float*)d_ws;
  float* gcol = (float*)((char*)d_ws + (size_t)4 * PTS * sizeof(float));
  uint4* afrag = (uint4*)((char*)gcol + (size_t)32 * 8 * N_ * sizeof(float));
  uint4* bfrag = afrag + (size_t)NTILES * 64;

  hipMemsetAsync(out, 0, sizeof(float), stream);
  pack_frags_k<<<512, 256, 0, stream>>>(x, y, afrag, bfrag);
  chamfer_main_k<<<1024, TPB, 0, stream>>>(afrag, bfrag, grow, gcol);
  chamfer_final_k<<<256, 256, 0, stream>>>(grow, gcol, out);
}